// Round 2
// baseline (458.896 us; speedup 1.0000x reference)
//
#include <hip/hip_runtime.h>

// x: (64, 512, 52, 52) fp32 -> out: (64, 512, 13, 13) fp32
// 4x4 window sum (stride 4), *1/32 (exact pow2), round-half-even, clip [-128,127].
// Memory-bound: 354 MB read + 22 MB write, every input byte touched exactly once.
//
// v2: 2 outputs per thread, split along the plane axis (plane p and p+16384).
// Same perfectly-coalesced read pattern as v1 (wave covers contiguous 208B row
// segments, every 64B line fully consumed within the wave), but 8 independent
// loads in flight per thread and half the index math / wave count.

#define PLANES      (64 * 512)          // 32768
#define H           52
#define W           52
#define OH          13
#define OW          13
#define PLANE_ELEMS (H * W)             // 2704
#define HALF_PLANES (PLANES / 2)        // 16384
#define HALF_OUT    (HALF_PLANES * OH * OW)  // 2768896
#define PLANE_OFF   ((size_t)HALF_PLANES * PLANE_ELEMS)

__global__ __launch_bounds__(256) void pool_sum_round_kernel(
    const float* __restrict__ x, float* __restrict__ out) {
    int idx = blockIdx.x * blockDim.x + threadIdx.x;
    if (idx >= HALF_OUT) return;

    int ow    = idx % OW;
    int t     = idx / OW;
    int oh    = t % OH;
    int plane = t / OH;

    const float* base0 = x + (size_t)plane * PLANE_ELEMS + (size_t)(oh * 4) * W + ow * 4;
    const float* base1 = base0 + PLANE_OFF;

    float4 v0[4], v1[4];
#pragma unroll
    for (int r = 0; r < 4; ++r)
        v0[r] = *reinterpret_cast<const float4*>(base0 + r * W);
#pragma unroll
    for (int r = 0; r < 4; ++r)
        v1[r] = *reinterpret_cast<const float4*>(base1 + r * W);

    float s0 = 0.0f, s1 = 0.0f;
#pragma unroll
    for (int r = 0; r < 4; ++r) {
        s0 += (v0[r].x + v0[r].y) + (v0[r].z + v0[r].w);
        s1 += (v1[r].x + v1[r].y) + (v1[r].z + v1[r].w);
    }

    float o0 = rintf(s0 * 0.03125f);
    float o1 = rintf(s1 * 0.03125f);
    o0 = fminf(fmaxf(o0, -128.0f), 127.0f);
    o1 = fminf(fmaxf(o1, -128.0f), 127.0f);
    __builtin_nontemporal_store(o0, out + idx);
    __builtin_nontemporal_store(o1, out + idx + HALF_OUT);
}

extern "C" void kernel_launch(void* const* d_in, const int* in_sizes, int n_in,
                              void* d_out, int out_size, void* d_ws, size_t ws_size,
                              hipStream_t stream) {
    const float* x = (const float*)d_in[0];
    float* out = (float*)d_out;
    int blocks = HALF_OUT / 256;   // 10816, exact
    pool_sum_round_kernel<<<blocks, 256, 0, stream>>>(x, out);
}